// Round 1
// baseline (197.505 us; speedup 1.0000x reference)
//
#include <hip/hip_runtime.h>
#include <stdint.h>

#define SS 4096
#define EE 256
// log2(e)/16  (logit scale 1/NORM_FACTOR folded into exp2 conversion)
#define C2 0.0901684273f

typedef __bf16 bf16x8 __attribute__((ext_vector_type(8)));
typedef float  f32x4  __attribute__((ext_vector_type(4)));

#if __has_builtin(__builtin_amdgcn_exp2f)
#define EXP2(x) __builtin_amdgcn_exp2f(x)
#else
#define EXP2(x) exp2f(x)
#endif

__device__ __forceinline__ uint16_t bf16_rn(float f) {
  uint32_t u = __float_as_uint(f);
  uint32_t r = (u + 0x7fffu + ((u >> 16) & 1u)) >> 16;
  return (uint16_t)r;
}
__device__ __forceinline__ float bf2f(uint16_t h) {
  return __uint_as_float(((uint32_t)h) << 16);
}

__device__ __forceinline__ f32x4 mfma16(bf16x8 a, bf16x8 b, f32x4 c) {
  return __builtin_amdgcn_mfma_f32_16x16x32_bf16(a, b, c, 0, 0, 0);
}

// Stage R rows x 512B (256 bf16/row) global -> LDS via global_load_lds(16B).
// XOR swizzle: logical 16B chunk cc of row r lands at physical chunk cc^(r&7)
// so frag reads (16 lanes hitting 16 rows at the same column) spread banks.
// LDS dest is wave-uniform base + lane*16 (m104/m108), so we swizzle the
// per-lane GLOBAL source address instead of the LDS layout.
template<int R>
__device__ __forceinline__ void stage_tile(const uint16_t* gsrc, char* lds, int tid) {
  constexpr int NPER = (R * 32) / 256;
  const int wave = tid >> 6;
  #pragma unroll
  for (int c = 0; c < NPER; ++c) {
    int chunk = c * 256 + tid;              // physical LDS chunk this lane fills
    int r = chunk >> 5;
    int ccl = (chunk & 31) ^ (r & 7);       // logical (global) chunk
    const char* gp = (const char*)gsrc + (r * 32 + ccl) * 16;
    char* lp = lds + (c * 256 + wave * 64) * 16;   // wave-uniform base
    __builtin_amdgcn_global_load_lds(
        (const __attribute__((address_space(1))) uint32_t*)(uintptr_t)gp,
        (__attribute__((address_space(3))) uint32_t*)(uintptr_t)lp,
        16, 0, 0);
  }
}

// Read one 16B frag chunk (logical chunk cc = kfrag*4 + quad) of tile row `row`.
__device__ __forceinline__ bf16x8 read_frag(const char* lds, int row, int cc) {
  int ccp = cc ^ (row & 7);
  return *(const bf16x8*)(lds + (row * 32 + ccp) * 16);
}

// ---------------- K0a: cast x fp32 -> bf16 ----------------
__global__ void xcast_kernel(const float* __restrict__ x, uint16_t* __restrict__ xb) {
  int i = blockIdx.x * 256 + threadIdx.x;   // over float4 groups; grid covers exactly
  float4 f = ((const float4*)x)[i];
  ushort4 o;
  o.x = bf16_rn(f.x); o.y = bf16_rn(f.y); o.z = bf16_rn(f.z); o.w = bf16_rn(f.w);
  ((ushort4*)xb)[i] = o;
}

// ---------------- K0b: transpose+cast W -> WT[out][in] bf16 ----------------
__global__ void wcast_kernel(const float* __restrict__ Wq, const float* __restrict__ Wk,
                             const float* __restrict__ Wv, uint16_t* __restrict__ wt) {
  int mat = blockIdx.y, o = blockIdx.x, i = threadIdx.x;
  const float* W = (mat == 0) ? Wq : (mat == 1) ? Wk : Wv;
  wt[((size_t)mat * 256 + o) * 256 + i] = bf16_rn(W[i * 256 + o]);
}

// ---------------- K1: fused QKV projection GEMM ----------------
// grid = M/64 = 256 WGs; WG loops 12 n-chunks of 64 over [Wq|Wk|Wv] (768 cols).
__global__ __launch_bounds__(256, 2) void qkv_kernel(
    const uint16_t* __restrict__ xb, const uint16_t* __restrict__ wt,
    const float* __restrict__ bq, const float* __restrict__ bk, const float* __restrict__ bv,
    uint16_t* __restrict__ qo, uint16_t* __restrict__ ko, uint16_t* __restrict__ vo) {
  __shared__ char xs[32768];
  __shared__ char wsm[2][32768];
  const int tid = threadIdx.x;
  const int lane = tid & 63, wave = tid >> 6, quad = lane >> 4, lr = lane & 15;
  const int m0 = blockIdx.x * 64;
  stage_tile<64>(xb + (size_t)m0 * EE, xs, tid);
  stage_tile<64>(wt, wsm[0], tid);
  __syncthreads();
  bf16x8 a[8];
  #pragma unroll
  for (int f = 0; f < 8; ++f)
    a[f] = read_frag(xs, wave * 16 + lr, f * 4 + quad);
  for (int nc = 0; nc < 12; ++nc) {
    if (nc + 1 < 12) stage_tile<64>(wt + (size_t)(nc + 1) * 64 * EE, wsm[(nc + 1) & 1], tid);
    const char* tile = wsm[nc & 1];
    const int mat = nc >> 2;
    const int e0 = (nc & 3) * 64;
    const float* bias = (mat == 0) ? bq : (mat == 1) ? bk : bv;
    uint16_t* outp = (mat == 0) ? qo : (mat == 1) ? ko : vo;
    #pragma unroll
    for (int nt = 0; nt < 4; ++nt) {
      f32x4 acc = {};
      #pragma unroll
      for (int f = 0; f < 8; ++f)
        acc = mfma16(a[f], read_frag(tile, nt * 16 + lr, f * 4 + quad), acc);
      const int e = e0 + nt * 16 + lr;
      const float bsv = bias[e];
      #pragma unroll
      for (int r = 0; r < 4; ++r) {
        int row = m0 + wave * 16 + quad * 4 + r;
        outp[(size_t)row * EE + e] = bf16_rn(acc[r] + bsv);
      }
    }
    __syncthreads();
  }
}

// ---------------- K2: pass A  l[s] = sum_t exp(q_s.k_t/16) ----------------
// grid = 4b x 16 qblk(256 rows) x 8 kchunk(512 keys) = 512 WGs.
// wave holds 64 q-rows as A-frags (128 VGPR); K streamed via dbuf LDS.
__global__ __launch_bounds__(256, 2) void scores_l_kernel(
    const uint16_t* __restrict__ q, const uint16_t* __restrict__ k,
    float* __restrict__ lacc) {
  __shared__ char kt[2][16384];
  const int tid = threadIdx.x;
  const int lane = tid & 63, wave = tid >> 6, quad = lane >> 4, lr = lane & 15;
  const int idx = blockIdx.x;
  const int b = idx >> 7, rem = idx & 127, qblk = rem >> 3, kch = rem & 7;
  const uint16_t* qb = q + (size_t)(b * SS + qblk * 256 + wave * 64) * EE;
  const uint16_t* kb = k + (size_t)(b * SS + kch * 512) * EE;
  bf16x8 a[4][8];
  #pragma unroll
  for (int ms = 0; ms < 4; ++ms)
    #pragma unroll
    for (int f = 0; f < 8; ++f)
      a[ms][f] = *(const bf16x8*)(qb + (size_t)(ms * 16 + lr) * EE + f * 32 + quad * 8);
  float accl[16];
  #pragma unroll
  for (int i = 0; i < 16; ++i) accl[i] = 0.f;
  stage_tile<32>(kb, kt[0], tid);
  for (int it = 0; it < 16; ++it) {
    __syncthreads();  // tile `it` drained; buffers from it-1 free
    if (it + 1 < 16) stage_tile<32>(kb + (size_t)(it + 1) * 32 * EE, kt[(it + 1) & 1], tid);
    const char* tile = kt[it & 1];
    #pragma unroll
    for (int nt = 0; nt < 2; ++nt) {
      bf16x8 bf[8];
      #pragma unroll
      for (int f = 0; f < 8; ++f) bf[f] = read_frag(tile, nt * 16 + lr, f * 4 + quad);
      f32x4 acc[4] = {};
      #pragma unroll
      for (int f = 0; f < 8; ++f)
        #pragma unroll
        for (int ms = 0; ms < 4; ++ms)
          acc[ms] = mfma16(a[ms][f], bf[f], acc[ms]);
      #pragma unroll
      for (int ms = 0; ms < 4; ++ms)
        #pragma unroll
        for (int r = 0; r < 4; ++r)
          accl[ms * 4 + r] += EXP2(acc[ms][r] * C2);
    }
  }
  #pragma unroll
  for (int d = 1; d < 16; d <<= 1)
    #pragma unroll
    for (int i = 0; i < 16; ++i)
      accl[i] += __shfl_xor(accl[i], d, 64);
  if (lr == 0) {
    float* lp = lacc + b * SS + qblk * 256 + wave * 64;
    #pragma unroll
    for (int ms = 0; ms < 4; ++ms)
      #pragma unroll
      for (int r = 0; r < 4; ++r)
        atomicAdd(&lp[ms * 16 + quad * 4 + r], accl[ms * 4 + r]);
  }
}

// ---------------- K2b: rl = 1/l ----------------
__global__ void rcp_kernel(const float* __restrict__ lacc, float* __restrict__ rl) {
  int i = blockIdx.x * 256 + threadIdx.x;
  rl[i] = 1.0f / lacc[i];
}

// ---------------- K3: pass B  w[t] = sum_s exp(q_s.k_t/16) * rl[s] ----------
// mirror of K2: wave holds 64 k-rows (A), q streamed (B), scores^T tile.
__global__ __launch_bounds__(256, 2) void scores_w_kernel(
    const uint16_t* __restrict__ q, const uint16_t* __restrict__ k,
    const float* __restrict__ rl, float* __restrict__ wacc) {
  __shared__ char qt[2][16384];
  const int tid = threadIdx.x;
  const int lane = tid & 63, wave = tid >> 6, quad = lane >> 4, lr = lane & 15;
  const int idx = blockIdx.x;
  const int b = idx >> 7, rem = idx & 127, kblk = rem >> 3, sch = rem & 7;
  const uint16_t* kb = k + (size_t)(b * SS + kblk * 256 + wave * 64) * EE;
  const uint16_t* qb = q + (size_t)(b * SS + sch * 512) * EE;
  const float* rlb = rl + b * SS + sch * 512;
  bf16x8 a[4][8];
  #pragma unroll
  for (int ms = 0; ms < 4; ++ms)
    #pragma unroll
    for (int f = 0; f < 8; ++f)
      a[ms][f] = *(const bf16x8*)(kb + (size_t)(ms * 16 + lr) * EE + f * 32 + quad * 8);
  float accw[16];
  #pragma unroll
  for (int i = 0; i < 16; ++i) accw[i] = 0.f;
  stage_tile<32>(qb, qt[0], tid);
  for (int it = 0; it < 16; ++it) {
    __syncthreads();
    if (it + 1 < 16) stage_tile<32>(qb + (size_t)(it + 1) * 32 * EE, qt[(it + 1) & 1], tid);
    const char* tile = qt[it & 1];
    #pragma unroll
    for (int nt = 0; nt < 2; ++nt) {
      float rlv = rlb[it * 32 + nt * 16 + lr];   // reciprocal row-sum for col s
      bf16x8 bf[8];
      #pragma unroll
      for (int f = 0; f < 8; ++f) bf[f] = read_frag(tile, nt * 16 + lr, f * 4 + quad);
      f32x4 acc[4] = {};
      #pragma unroll
      for (int f = 0; f < 8; ++f)
        #pragma unroll
        for (int ms = 0; ms < 4; ++ms)
          acc[ms] = mfma16(a[ms][f], bf[f], acc[ms]);
      #pragma unroll
      for (int ms = 0; ms < 4; ++ms)
        #pragma unroll
        for (int r = 0; r < 4; ++r)
          accw[ms * 4 + r] += EXP2(acc[ms][r] * C2) * rlv;
    }
  }
  #pragma unroll
  for (int d = 1; d < 16; d <<= 1)
    #pragma unroll
    for (int i = 0; i < 16; ++i)
      accw[i] += __shfl_xor(accw[i], d, 64);
  if (lr == 0) {
    float* wp = wacc + b * SS + kblk * 256 + wave * 64;
    #pragma unroll
    for (int ms = 0; ms < 4; ++ms)
      #pragma unroll
      for (int r = 0; r < 4; ++r)
        atomicAdd(&wp[ms * 16 + quad * 4 + r], accw[ms * 4 + r]);
  }
}

// ---------------- K4: out[b,e] = (1/S) sum_t w[t] v[t,e] ----------------
__global__ void pool_kernel(const float* __restrict__ wsum, const uint16_t* __restrict__ v,
                            float* __restrict__ out) {
  const int b = blockIdx.x >> 4, tc = blockIdx.x & 15;
  const int tr = threadIdx.x >> 6, eg = threadIdx.x & 63;
  float acc[4] = {0.f, 0.f, 0.f, 0.f};
  const float* wp = wsum + b * SS + tc * 256;
  const uint16_t* vp = v + (size_t)(b * SS + tc * 256) * EE;
  for (int t = tr; t < 256; t += 4) {
    float wv = wp[t];
    ushort4 x4 = *(const ushort4*)(vp + (size_t)t * EE + eg * 4);
    acc[0] += wv * bf2f(x4.x);
    acc[1] += wv * bf2f(x4.y);
    acc[2] += wv * bf2f(x4.z);
    acc[3] += wv * bf2f(x4.w);
  }
  const float inv = 1.0f / 4096.0f;
  #pragma unroll
  for (int j = 0; j < 4; ++j)
    atomicAdd(&out[b * 256 + eg * 4 + j], acc[j] * inv);
}

// ---------------- launch ----------------
extern "C" void kernel_launch(void* const* d_in, const int* in_sizes, int n_in,
                              void* d_out, int out_size, void* d_ws, size_t ws_size,
                              hipStream_t stream) {
  const float* x  = (const float*)d_in[0];
  const float* Wq = (const float*)d_in[1];
  const float* bq = (const float*)d_in[2];
  const float* Wk = (const float*)d_in[3];
  const float* bk = (const float*)d_in[4];
  const float* Wv = (const float*)d_in[5];
  const float* bv = (const float*)d_in[6];

  char* ws = (char*)d_ws;
  uint16_t* xb   = (uint16_t*)(ws);              //  8 MB  x bf16
  uint16_t* qb   = (uint16_t*)(ws + 8388608);    //  8 MB  q bf16
  uint16_t* kb   = (uint16_t*)(ws + 16777216);   //  8 MB  k bf16
  uint16_t* vb   = (uint16_t*)(ws + 25165824);   //  8 MB  v bf16
  uint16_t* wt   = (uint16_t*)(ws + 33554432);   // 384 KB WT bf16 (q|k|v transposed)
  float* l_arr   = (float*)(ws + 33947648);      // 64 KB
  float* rl_arr  = (float*)(ws + 34013184);      // 64 KB
  float* w_arr   = (float*)(ws + 34078720);      // 64 KB  (total ws use ~32.6 MB)
  float* out     = (float*)d_out;

  hipMemsetAsync(l_arr, 0, 3 * 65536, stream);   // zeros l, rl, w
  hipMemsetAsync(out, 0, 1024 * sizeof(float), stream);

  xcast_kernel<<<4096, 256, 0, stream>>>(x, xb);                        // 4.19M elems /4
  wcast_kernel<<<dim3(256, 3), 256, 0, stream>>>(Wq, Wk, Wv, wt);
  qkv_kernel<<<256, 256, 0, stream>>>(xb, wt, bq, bk, bv, qb, kb, vb);
  scores_l_kernel<<<512, 256, 0, stream>>>(qb, kb, l_arr);
  rcp_kernel<<<64, 256, 0, stream>>>(l_arr, rl_arr);
  scores_w_kernel<<<512, 256, 0, stream>>>(qb, kb, rl_arr, w_arr);
  pool_kernel<<<64, 256, 0, stream>>>(w_arr, vb, out);
}